// Round 3
// baseline (377.763 us; speedup 1.0000x reference)
//
#include <hip/hip_runtime.h>
#include <math.h>

// LBP radius=1, n_points=8 on NCHW (16,64,224,224) f32.
// Sliding-window column strips: each thread owns a 4-wide strip, walks 28
// rows with a 4-row register window; loads row r+2 while computing row r
// (software pipeline). p=0,2,4,6 exact neighbor compares; p=1,3,5,7 bilinear
// diagonals, bit-exact vs numpy f32 (per-term rounding, L-to-R sum, no FMA).
#define HH 224
#define WW 224
#define PLANES (16 * 64)
#define TILES_X 56                 // 224/4 strips per row
#define STRIPS_Y 8                 // 224/28 strips per column
#define RSTRIP 28
#define SPP (TILES_X * STRIPS_Y)   // 448 strips per plane
#define TOTAL_THREADS (PLANES * SPP)  // 458,752 = 1792 blocks * 256

typedef float f4v __attribute__((ext_vector_type(4)));

struct LbpWeights {
    float w1[4];
    float w3[4];
    float w5[4];
    float w7[4];
};

__device__ __forceinline__ void load_row6(const float* __restrict__ pb, int rr,
                                          int c0, bool cm, bool cp, float w[6]) {
    if ((unsigned)rr < (unsigned)HH) {
        const float* rp = pb + rr * WW + c0;
        float4 v = *(const float4*)rp;
        w[1] = v.x; w[2] = v.y; w[3] = v.z; w[4] = v.w;
        w[0] = cm ? rp[-1] : 0.0f;
        w[5] = cp ? rp[4]  : 0.0f;
    } else {
        w[0] = w[1] = w[2] = w[3] = w[4] = w[5] = 0.0f;
    }
}

// a = row r-1, b = row r (centers), c = row r+1; writes 4 codes at op.
__device__ __forceinline__ void compute_store(const float a[6], const float b[6],
                                              const float c[6],
                                              const LbpWeights& wt,
                                              float* __restrict__ op) {
    float res[4];
#pragma unroll
    for (int k = 0; k < 4; k++) {
        float ctr = b[k + 1];
        float n00 = a[k], n01 = a[k + 1], n02 = a[k + 2];
        float n10 = b[k],                 n12 = b[k + 2];
        float n20 = c[k], n21 = c[k + 1], n22 = c[k + 2];

        float v1, v3, v5, v7;
        {
#pragma clang fp contract(off)
            // p=1: r0=-1,c0=0 -> (n01, n02, ctr, n12)
            v1 = ((wt.w1[0] * n01 + wt.w1[1] * n02) + wt.w1[2] * ctr) + wt.w1[3] * n12;
            // p=3: r0=-1,c0=-1 -> (n00, n01, n10, ctr)
            v3 = ((wt.w3[0] * n00 + wt.w3[1] * n01) + wt.w3[2] * n10) + wt.w3[3] * ctr;
            // p=5: r0=0,c0=-1 -> (n10, ctr, n20, n21)
            v5 = ((wt.w5[0] * n10 + wt.w5[1] * ctr) + wt.w5[2] * n20) + wt.w5[3] * n21;
            // p=7: r0=0,c0=0 -> (ctr, n12, n21, n22)
            v7 = ((wt.w7[0] * ctr + wt.w7[1] * n12) + wt.w7[2] * n21) + wt.w7[3] * n22;
        }

        int m = 0;
        m |= (n12 >= ctr) ? 1   : 0;
        m |= (v1  >= ctr) ? 2   : 0;
        m |= (n01 >= ctr) ? 4   : 0;
        m |= (v3  >= ctr) ? 8   : 0;
        m |= (n10 >= ctr) ? 16  : 0;
        m |= (v5  >= ctr) ? 32  : 0;
        m |= (n21 >= ctr) ? 64  : 0;
        m |= (v7  >= ctr) ? 128 : 0;
        res[k] = (float)m;
    }
    f4v o;
    o.x = res[0]; o.y = res[1]; o.z = res[2]; o.w = res[3];
    __builtin_nontemporal_store(o, (f4v*)op);  // output never re-read; keep input in L3
}

__global__ __launch_bounds__(256, 8) void lbp_kernel(const float* __restrict__ x,
                                                     float* __restrict__ out,
                                                     LbpWeights wt) {
    int tid = blockIdx.x * 256 + threadIdx.x;
    int plane = tid / SPP;
    int s = tid - plane * SPP;
    int sr = s / TILES_X;
    int tc = s - sr * TILES_X;
    int c0 = tc * 4;
    int r0 = sr * RSTRIP;

    const float* pb = x + (size_t)plane * (HH * WW);
    float* op = out + (size_t)plane * (HH * WW) + (size_t)r0 * WW + c0;
    bool cm = (c0 > 0), cp = (c0 + 4 < WW);

    float w0[6], w1[6], w2[6], w3[6];
    load_row6(pb, r0 - 1, c0, cm, cp, w0);  // zero when r0==0
    load_row6(pb, r0,     c0, cm, cp, w1);
    load_row6(pb, r0 + 1, c0, cm, cp, w2);  // r0+1 <= 197, always valid

    int r = r0;
#pragma unroll 1
    for (int g = 0; g < 7; ++g) {
        // step s computes row r0+s from regs, loads row r0+s+2 (bounds-checked)
        load_row6(pb, r + 2, c0, cm, cp, w3);
        compute_store(w0, w1, w2, wt, op); op += WW;
        load_row6(pb, r + 3, c0, cm, cp, w0);
        compute_store(w1, w2, w3, wt, op); op += WW;
        load_row6(pb, r + 4, c0, cm, cp, w1);
        compute_store(w2, w3, w0, wt, op); op += WW;
        load_row6(pb, r + 5, c0, cm, cp, w2);
        compute_store(w3, w0, w1, wt, op); op += WW;
        r += 4;
    }
}

extern "C" void kernel_launch(void* const* d_in, const int* in_sizes, int n_in,
                              void* d_out, int out_size, void* d_ws, size_t ws_size,
                              hipStream_t stream) {
    (void)in_sizes; (void)n_in; (void)d_ws; (void)ws_size; (void)out_size;
    const float* x = (const float*)d_in[0];
    float* out = (float*)d_out;

    // Replicate np.round(-R*sin(ang), 8) = rint(v*1e8)/1e8 in double; weights
    // are float64 products rounded to f32 (NEP-50 weak-scalar semantics).
    LbpWeights wt;
    float* slots[4] = {wt.w1, wt.w3, wt.w5, wt.w7};
    const int diag_p[4] = {1, 3, 5, 7};
    for (int i = 0; i < 4; i++) {
        int p = diag_p[i];
        double ang = (2.0 * M_PI * (double)p) / 8.0;
        double dr = rint(-sin(ang) * 1e8) / 1e8;
        double dc = rint( cos(ang) * 1e8) / 1e8;
        double r0 = floor(dr), c0 = floor(dc);
        double fr = dr - r0, fc = dc - c0;
        slots[i][0] = (float)((1.0 - fr) * (1.0 - fc));
        slots[i][1] = (float)((1.0 - fr) * fc);
        slots[i][2] = (float)(fr * (1.0 - fc));
        slots[i][3] = (float)(fr * fc);
    }

    const int block = 256;
    const int grid = TOTAL_THREADS / block;  // 1792, exact; 7 blocks/CU
    lbp_kernel<<<grid, block, 0, stream>>>(x, out, wt);
}

// Round 4
// 372.207 us; speedup vs baseline: 1.0149x; 1.0149x over previous
//
#include <hip/hip_runtime.h>
#include <math.h>

// LBP radius=1, n_points=8 on NCHW (16,64,224,224) f32.
// 8x4 register tile per thread; 24 fully-independent loads per thread (max
// MLP), branchless clamped border loads, shared bilinear products.
// p=0,2,4,6 exact neighbor compares; p=1,3,5,7 bilinear diagonals, bit-exact
// vs numpy f32 (per-term rounding, left-to-right sums, no FMA contraction;
// product reuse is bit-safe since identical f32 products round identically).
#define HH 224
#define WW 224
#define TW 8
#define TH 4
#define TILES_X (WW / TW)            // 28
#define TILES_Y (HH / TH)            // 56
#define TPP (TILES_X * TILES_Y)      // 1568 tiles per plane
#define PLANES (16 * 64)
#define TOTAL_THREADS (PLANES * TPP) // 1,605,632 = 6272 * 256

typedef float f4v __attribute__((ext_vector_type(4)));

__global__ __launch_bounds__(256) void lbp_kernel(const float* __restrict__ x,
                                                  float* __restrict__ out,
                                                  float A, float B, float C) {
    int tid = blockIdx.x * 256 + threadIdx.x;
    int plane = tid / TPP;
    int t = tid - plane * TPP;
    int ty = t / TILES_X;
    int tx = t - ty * TILES_X;
    int r0 = ty * TH, c0 = tx * TW;

    const float* pb = x + (size_t)plane * (HH * WW);
    bool cm = (c0 > 0), cp = (c0 + TW < WW);
    // Branchless in-bounds border offsets; value zeroed at use if edge.
    int loff = cm ? -1 : 0;
    int roff = cp ? TW : TW - 1;

    // Window rows r0-1..r0+4, cols c0-1..c0+8 (zero outside image).
    float w[6][10];
#pragma unroll
    for (int i = 0; i < 6; i++) {
        int rr = r0 - 1 + i;
        if ((unsigned)rr < (unsigned)HH) {
            const float* rp = pb + rr * WW + c0;
            f4v v0 = *(const f4v*)rp;
            f4v v1 = *(const f4v*)(rp + 4);
            float lv = rp[loff];
            float rv = rp[roff];
            w[i][0] = cm ? lv : 0.0f;
            w[i][1] = v0.x; w[i][2] = v0.y; w[i][3] = v0.z; w[i][4] = v0.w;
            w[i][5] = v1.x; w[i][6] = v1.y; w[i][7] = v1.z; w[i][8] = v1.w;
            w[i][9] = cp ? rv : 0.0f;
        } else {
#pragma unroll
            for (int k = 0; k < 10; k++) w[i][k] = 0.0f;
        }
    }

    float* ob = out + (size_t)plane * (HH * WW) + (size_t)r0 * WW + c0;

#pragma unroll
    for (int j = 0; j < TH; j++) {
        float res[TW];
#pragma unroll
        for (int k = 0; k < TW; k++) {
            float ctr = w[j + 1][k + 1];
            float n00 = w[j][k],     n01 = w[j][k + 1],     n02 = w[j][k + 2];
            float n10 = w[j + 1][k],                        n12 = w[j + 1][k + 2];
            float n20 = w[j + 2][k], n21 = w[j + 2][k + 1], n22 = w[j + 2][k + 2];

            float v1, v3, v5, v7;
            {
#pragma clang fp contract(off)
                // Shared products (identical f32 roundings reused — bit-safe).
                float q   = C * ctr;
                float b01 = B * n01;
                float b12 = B * n12;
                float b10 = B * n10;
                float b21 = B * n21;
                // p=1 w={B,A,C,B}: ((B*n01 + A*n02) + C*ctr) + B*n12
                v1 = ((b01 + A * n02) + q) + b12;
                // p=3 w={A,B,B,C}: ((A*n00 + B*n01) + B*n10) + C*ctr
                v3 = ((A * n00 + b01) + b10) + q;
                // p=5 w={B,C,A,B}: ((B*n10 + C*ctr) + A*n20) + B*n21
                v5 = ((b10 + q) + A * n20) + b21;
                // p=7 w={C,B,B,A}: ((C*ctr + B*n12) + B*n21) + A*n22
                v7 = ((q + b12) + b21) + A * n22;
            }

            int m = 0;
            m |= (n12 >= ctr) ? 1   : 0;
            m |= (v1  >= ctr) ? 2   : 0;
            m |= (n01 >= ctr) ? 4   : 0;
            m |= (v3  >= ctr) ? 8   : 0;
            m |= (n10 >= ctr) ? 16  : 0;
            m |= (v5  >= ctr) ? 32  : 0;
            m |= (n21 >= ctr) ? 64  : 0;
            m |= (v7  >= ctr) ? 128 : 0;
            res[k] = (float)m;
        }
        f4v o0, o1;
        o0.x = res[0]; o0.y = res[1]; o0.z = res[2]; o0.w = res[3];
        o1.x = res[4]; o1.y = res[5]; o1.z = res[6]; o1.w = res[7];
        *(f4v*)(ob + j * WW) = o0;       // regular stores: let L2 merge lines
        *(f4v*)(ob + j * WW + 4) = o1;
    }
}

extern "C" void kernel_launch(void* const* d_in, const int* in_sizes, int n_in,
                              void* d_out, int out_size, void* d_ws, size_t ws_size,
                              hipStream_t stream) {
    (void)in_sizes; (void)n_in; (void)d_ws; (void)ws_size; (void)out_size;
    const float* x = (const float*)d_in[0];
    float* out = (float*)d_out;

    // Replicate np.round(-R*sin(ang),8)=rint(v*1e8)/1e8 in f64 for p=1; its
    // weight set {st, ss, tt, ts} yields the three distinct f32 constants
    // shared (as identical f64 products) by all four diagonal points.
    double ang = 2.0 * M_PI / 8.0;
    double dr = rint(-sin(ang) * 1e8) / 1e8;   // -0.70710678
    double dc = rint( cos(ang) * 1e8) / 1e8;   //  0.70710678
    double fr = dr - floor(dr), fc = dc - floor(dc);
    float wB = (float)((1.0 - fr) * (1.0 - fc));  // s*t
    float wA = (float)((1.0 - fr) * fc);          // s*s
    float wC = (float)(fr * (1.0 - fc));          // t*t

    const int block = 256;
    const int grid = TOTAL_THREADS / block;  // 6272, exact
    lbp_kernel<<<grid, block, 0, stream>>>(x, out, wA, wB, wC);
}